// Round 10
// baseline (142.000 us; speedup 1.0000x reference)
//
#include <hip/hip_runtime.h>

#define B_    32
#define H_    640
#define W_    368
#define OH    634          // H - 6
#define OW    362          // W - 6
#define CHUNK 7            // output rows per block (one unrolled pass)
#define NCHUNK 91          // 90 full chunks + last (4 rows); 90*7+4 = 634
#define NBLK  (NCHUNK * B_)          // 2912 = 45*64 + 32
#define GROUPS 64

// d_ws layout (floats):
//   [0..31]      per-batch max of target (int-bits atomicMax; 0xAA poison is negative,
//                any positive-float bits win, so no pre-zeroing needed)
//   [64..1087]   64 partial-sum slots, stride 16 floats (64 B); zeroed by k_max blk 0
//   [1088..2111] 64 group counters (uint), stride 16 (separate lines); zeroed by k_max blk 0
//   [2112]       root counter (uint, own line); zeroed by k_max blk 0
#define SLOT0 64
#define CNT0  1088
#define ROOTC 2112
#define STRIDE 16

typedef float f2 __attribute__((ext_vector_type(2)));
__device__ __forceinline__ f2 ffma2(f2 a, f2 b, f2 c) { return __builtin_elementwise_fma(a, b, c); }

__global__ __launch_bounds__(256) void k_max(const float* __restrict__ tgt,
                                             float* __restrict__ ws) {
    if (blockIdx.x == 0) {                     // zero slots + counters (stream order vs k_ssim)
        for (int i = threadIdx.x; i < 2 * GROUPS * STRIDE + STRIDE; i += 256)
            ws[SLOT0 + i] = 0.0f;
    }
    const int b   = blockIdx.x >> 6;           // 64 segments per batch
    const int seg = blockIdx.x & 63;
    const int perseg = (H_ * W_) / 64;         // 3680 floats
    const float4* p = (const float4*)(tgt + (size_t)b * (H_ * W_) + (size_t)seg * perseg);
    const int n4 = perseg / 4;                 // 920
    float m = 0.0f;
    for (int i = threadIdx.x; i < n4; i += 256) {
        float4 v = p[i];
        m = fmaxf(m, fmaxf(fmaxf(v.x, v.y), fmaxf(v.z, v.w)));
    }
    #pragma unroll
    for (int off = 32; off; off >>= 1)
        m = fmaxf(m, __shfl_down(m, off, 64));
    __shared__ float sm[4];
    const int lane = threadIdx.x & 63, wv = threadIdx.x >> 6;
    if (lane == 0) sm[wv] = m;
    __syncthreads();
    if (threadIdx.x == 0) {
        m = fmaxf(fmaxf(sm[0], sm[1]), fmaxf(sm[2], sm[3]));
        atomicMax((int*)ws + b, __float_as_int(m));   // inputs >= 0
    }
}

__device__ __forceinline__ void loadrow(const float* __restrict__ xr,
                                        const float* __restrict__ yr,
                                        f2 xn[4], f2 yn[4]) {
    const f2* xp = (const f2*)xr;   // (r*368 + 2t)*4 is always 8B-aligned
    const f2* yp = (const f2*)yr;
    xn[0] = xp[0]; xn[1] = xp[1]; xn[2] = xp[2]; xn[3] = xp[3];
    yn[0] = yp[0]; yn[1] = yp[1]; yn[2] = yp[2]; yn[3] = yp[3];
}

// Horizontal 7-sums for TWO adjacent windows (cols c..c+6, c+1..c+7), packed
// into f2 lanes {win0, win1} per quantity: h = {x, y, xx, yy, xy}.
__device__ __forceinline__ void hsum2v(const f2 xn[4], const f2 yn[4], f2 h[5]) {
    const float xs[8] = {xn[0].x, xn[0].y, xn[1].x, xn[1].y, xn[2].x, xn[2].y, xn[3].x, xn[3].y};
    const float ys[8] = {yn[0].x, yn[0].y, yn[1].x, yn[1].y, yn[2].x, yn[2].y, yn[3].x, yn[3].y};
    float hx = 0, hy = 0, hxx = 0, hyy = 0, hxy = 0;
    #pragma unroll
    for (int k = 0; k < 7; ++k) {
        const float xv = xs[k], yv = ys[k];
        hx += xv; hy += yv;
        hxx = fmaf(xv, xv, hxx);
        hyy = fmaf(yv, yv, hyy);
        hxy = fmaf(xv, yv, hxy);
    }
    h[0] = f2{hx,  hx - xs[0] + xs[7]};
    h[1] = f2{hy,  hy - ys[0] + ys[7]};
    h[2] = f2{hxx, fmaf(xs[7], xs[7], fmaf(-xs[0], xs[0], hxx))};
    h[3] = f2{hyy, fmaf(ys[7], ys[7], fmaf(-ys[0], ys[0], hyy))};
    h[4] = f2{hxy, fmaf(xs[7], ys[7], fmaf(-xs[0], ys[0], hxy))};
}

// NOTE: no min-waves clamp — a forced VGPR=64 spilled the ring in R6 (WRITE_SIZE
// 96 KB -> 120 MB). The f2 form landed at 64 VGPR spill-free in R8/R9.
__global__ __launch_bounds__(192) void k_ssim(const float* __restrict__ X,
                                              const float* __restrict__ Y,
                                              float* __restrict__ ws,
                                              float* __restrict__ out) {
    const int t    = threadIdx.x;              // 0..191
    const int w    = t >> 6;
    const int lane = t & 63;
    const int b    = blockIdx.y;
    const int r0   = blockIdx.x * CHUNK;
    const int outRows = min(CHUNK, OH - r0);   // 7, or 4 for last chunk
    const int c    = 2 * t;                    // base output col
    const bool colOK = (c < OW);               // t <= 180

    const float dr  = ws[b];
    float C1 = 0.01f * dr; C1 *= C1;
    float C2 = 0.03f * dr; C2 *= C2;
    const f2 c1v = f2{C1 * 2401.0f, C1 * 2401.0f};   // scaled-domain constants
    const f2 c2v = f2{C2 * 2401.0f, C2 * 2401.0f};
    const f2 two    = f2{2.0f, 2.0f};
    const f2 k49    = f2{49.0f, 49.0f};
    const f2 covn2v = f2{2.0f * (49.0f / 48.0f), 2.0f * (49.0f / 48.0f)};
    const f2 covnv  = f2{49.0f / 48.0f, 49.0f / 48.0f};

    const float* xb = X + (size_t)b * (H_ * W_) + c;
    const float* yb = Y + (size_t)b * (H_ * W_) + c;

    f2 acc2 = f2{0.0f, 0.0f};

    if (colOK) {
        f2 ring[5][7];                         // [quantity][row slot], lanes = 2 cols
        f2 tot[5] = {f2{0,0}, f2{0,0}, f2{0,0}, f2{0,0}, f2{0,0}};
        f2 h[5];
        f2 xn0[4], yn0[4], xn1[4], yn1[4];     // depth-2 prefetch pipeline

        #pragma unroll
        for (int p = 0; p < 6; ++p) {          // prime 6 halo rows
            loadrow(xb + (size_t)(r0 + p) * W_, yb + (size_t)(r0 + p) * W_, xn0, yn0);
            hsum2v(xn0, yn0, h);
            #pragma unroll
            for (int q = 0; q < 5; ++q) { ring[q][p] = h[q]; tot[q] += h[q]; }
        }
        // preload rows r0+6 (parity 0) and r0+7 (parity 1)
        loadrow(xb + (size_t)(r0 + 6) * W_, yb + (size_t)(r0 + 6) * W_, xn0, yn0);
        {
            int r7 = r0 + 7; if (r7 > H_ - 1) r7 = H_ - 1;   // clamped: value unused if OOB row
            loadrow(xb + (size_t)r7 * W_, yb + (size_t)r7 * W_, xn1, yn1);
        }

        #pragma unroll
        for (int p = 0; p < 7; ++p) {          // single pass: CHUNK == 7
            if (p >= outRows) break;           // block-uniform
            // consume buffer parity p&1 (holds row r0+p+6)
            if ((p & 1) == 0) hsum2v(xn0, yn0, h);
            else              hsum2v(xn1, yn1, h);
            // prefetch row r0+p+8 into the just-consumed buffer (used at iter p+2)
            {
                int rp = r0 + p + 8; if (rp > H_ - 1) rp = H_ - 1;   // clamp: extra read harmless
                if ((p & 1) == 0) loadrow(xb + (size_t)rp * W_, yb + (size_t)rp * W_, xn0, yn0);
                else              loadrow(xb + (size_t)rp * W_, yb + (size_t)rp * W_, xn1, yn1);
            }

            #pragma unroll
            for (int q = 0; q < 5; ++q) tot[q] += h[q];

            const f2 tx = tot[0], ty = tot[1], txx = tot[2], tyy = tot[3], txy = tot[4];
            const f2 pxy = tx * ty;
            const f2 A1  = ffma2(pxy, two, c1v);
            const f2 s2  = ffma2(tx, tx, ty * ty);
            const f2 B1  = s2 + c1v;
            const f2 mxy = ffma2(k49, txy, -pxy);
            const f2 A2  = ffma2(covn2v, mxy, c2v);
            const f2 vs  = ffma2(k49, txx + tyy, -s2);
            const f2 B2  = ffma2(covnv, vs, c2v);
            const f2 num = A1 * A2;
            const f2 den = B1 * B2;
            f2 r;
            r.x = __builtin_amdgcn_rcpf(den.x);
            r.y = __builtin_amdgcn_rcpf(den.y);
            acc2 = ffma2(num, r, acc2);

            #pragma unroll
            for (int q = 0; q < 5; ++q) { tot[q] -= ring[q][p]; ring[q][p] = h[q]; }
        }
    }

    float acc = acc2.x + acc2.y;
    #pragma unroll
    for (int off = 32; off; off >>= 1)
        acc += __shfl_down(acc, off, 64);
    __shared__ float sm[3];
    if (lane == 0) sm[w] = acc;
    __syncthreads();
    if (t == 0) {
        const float s = sm[0] + sm[1] + sm[2];
        const int blk = blockIdx.y * NCHUNK + blockIdx.x;
        const unsigned g = (unsigned)(blk & (GROUPS - 1));
        float* slots = ws + SLOT0;
        // Hierarchical completion: 64 parallel group counters, then 64-RMW root.
        // (Single-address counter serialized 2048 RMWs ~62 us in R8.) s_waitcnt is a
        // wave-local drain ordering add -> count; no buffer_inv (threadfence killed R5).
        atomicAdd(&slots[g * STRIDE], s);      // 64 independent lines
        __builtin_amdgcn_s_waitcnt(0);         // slot add at L2 before counting
        unsigned* cnt1 = (unsigned*)(ws + CNT0);
        const unsigned d1 = atomicAdd(&cnt1[g * STRIDE], 1u);
        // NBLK = 2912 = 45*64 + 32: groups 0..31 have 46 blocks, 32..63 have 45
        const unsigned target = (NBLK >> 6) + (g < (NBLK & 63u) ? 1u : 0u);
        if (d1 == target - 1) {                // group complete
            __builtin_amdgcn_s_waitcnt(0);
            const unsigned d2 = atomicAdd((unsigned*)(ws + ROOTC), 1u);
            if (d2 == GROUPS - 1) {            // all groups complete: finalize
                float totsum = 0.0f;
                #pragma unroll
                for (int i = 0; i < GROUPS; ++i)
                    totsum += atomicAdd(&slots[i * STRIDE], 0.0f);   // L2-coherent reads
                out[0] = 1.0f - totsum * (1.0f / (32.0f * 634.0f * 362.0f));
            }
        }
    }
}

extern "C" void kernel_launch(void* const* d_in, const int* in_sizes, int n_in,
                              void* d_out, int out_size, void* d_ws, size_t ws_size,
                              hipStream_t stream) {
    const float* X = (const float*)d_in[0];   // 'output'
    const float* Y = (const float*)d_in[1];   // 'target'
    float* ws = (float*)d_ws;

    k_max<<<dim3(2048), dim3(256), 0, stream>>>(Y, ws);
    k_ssim<<<dim3(NCHUNK, B_), dim3(192), 0, stream>>>(X, Y, ws, (float*)d_out);
}

// Round 11
// 141.810 us; speedup vs baseline: 1.0013x; 1.0013x over previous
//
#include <hip/hip_runtime.h>

#define B_    32
#define H_    640
#define W_    368
#define OH    634          // H - 6
#define OW    362          // W - 6
#define CHUNK 20           // output rows per block
#define NCHUNK 32          // 31 full chunks + last (14 rows); 31*20+14 = 634
#define NBLK  (NCHUNK * B_)          // 1024
#define GROUPS 64
#define PER_GROUP (NBLK / GROUPS)    // 16

// d_ws layout (floats):
//   [0..31]      per-batch max of target (int-bits atomicMax; 0xAA poison is negative,
//                any positive-float bits win, so no pre-zeroing needed)
//   [64..1087]   64 partial-sum slots, stride 16 floats (64 B); zeroed by k_max blk 0
//   [1088..2111] 64 group counters (uint), stride 16; zeroed by k_max blk 0
//   [2112]       root counter (uint, own line); zeroed by k_max blk 0
#define SLOT0 64
#define CNT0  1088
#define ROOTC 2112
#define STRIDE 16

typedef float f2 __attribute__((ext_vector_type(2)));
typedef float f4 __attribute__((ext_vector_type(4)));
__device__ __forceinline__ f2 ffma2(f2 a, f2 b, f2 c) { return __builtin_elementwise_fma(a, b, c); }

__global__ __launch_bounds__(256) void k_max(const float* __restrict__ tgt,
                                             float* __restrict__ ws) {
    if (blockIdx.x == 0) {                     // zero slots + counters (stream order vs k_ssim)
        for (int i = threadIdx.x; i < 2 * GROUPS * STRIDE + STRIDE; i += 256)
            ws[SLOT0 + i] = 0.0f;
    }
    const int b   = blockIdx.x >> 6;           // 64 segments per batch
    const int seg = blockIdx.x & 63;
    const int perseg = (H_ * W_) / 64;         // 3680 floats
    const float4* p = (const float4*)(tgt + (size_t)b * (H_ * W_) + (size_t)seg * perseg);
    const int n4 = perseg / 4;                 // 920
    float m = 0.0f;
    for (int i = threadIdx.x; i < n4; i += 256) {
        float4 v = p[i];
        m = fmaxf(m, fmaxf(fmaxf(v.x, v.y), fmaxf(v.z, v.w)));
    }
    #pragma unroll
    for (int off = 32; off; off >>= 1)
        m = fmaxf(m, __shfl_down(m, off, 64));
    __shared__ float sm[4];
    const int lane = threadIdx.x & 63, wv = threadIdx.x >> 6;
    if (lane == 0) sm[wv] = m;
    __syncthreads();
    if (threadIdx.x == 0) {
        m = fmaxf(fmaxf(sm[0], sm[1]), fmaxf(sm[2], sm[3]));
        atomicMax((int*)ws + b, __float_as_int(m));   // inputs >= 0
    }
}

// Horizontal 7-sums for TWO adjacent windows (cols c..c+6, c+1..c+7) read from
// LDS row pointers (8-byte aligned: (row*368 + 2t)*4). h = {x, y, xx, yy, xy}
// packed as f2 lanes {win0, win1}.
__device__ __forceinline__ void hsum2l(const float* __restrict__ xr,
                                       const float* __restrict__ yr,
                                       f2 h[5]) {
    float xs[8], ys[8];
    #pragma unroll
    for (int k = 0; k < 4; ++k) {
        const f2 a = ((const f2*)xr)[k];
        const f2 d = ((const f2*)yr)[k];
        xs[2*k] = a.x; xs[2*k+1] = a.y;
        ys[2*k] = d.x; ys[2*k+1] = d.y;
    }
    float hx = 0, hy = 0, hxx = 0, hyy = 0, hxy = 0;
    #pragma unroll
    for (int k = 0; k < 7; ++k) {
        const float xv = xs[k], yv = ys[k];
        hx += xv; hy += yv;
        hxx = fmaf(xv, xv, hxx);
        hyy = fmaf(yv, yv, hyy);
        hxy = fmaf(xv, yv, hxy);
    }
    h[0] = f2{hx,  hx - xs[0] + xs[7]};
    h[1] = f2{hy,  hy - ys[0] + ys[7]};
    h[2] = f2{hxx, fmaf(xs[7], xs[7], fmaf(-xs[0], xs[0], hxx))};
    h[3] = f2{hyy, fmaf(ys[7], ys[7], fmaf(-ys[0], ys[0], hyy))};
    h[4] = f2{hxy, fmaf(xs[7], ys[7], fmaf(-xs[0], ys[0], hxy))};
}

// LDS-staged SSIM: 184 threads cooperatively stage each row (x+y = 184 dwordx4
// = 3 wave-insts) into an 8-slot LDS ring; 181 compute threads run the f2
// column-sum ring fed by ds_read_b64. ~9x fewer VMEM insts than private loads
// (R9/R10 showed wall ~ 32.5 ns x wave-VMEM-insts, L3-warm replays no faster).
__global__ __launch_bounds__(256) void k_ssim(const float* __restrict__ X,
                                              const float* __restrict__ Y,
                                              float* __restrict__ ws,
                                              float* __restrict__ out) {
    const int t    = threadIdx.x;              // 0..255
    const int w    = t >> 6;
    const int lane = t & 63;
    const int b    = blockIdx.y;
    const int r0   = blockIdx.x * CHUNK;
    const int outRows = min(CHUNK, OH - r0);   // 20, or 14 for last chunk

    __shared__ __align__(16) float lx[8][W_];  // 8-row ring, x
    __shared__ __align__(16) float ly[8][W_];  // 8-row ring, y

    // staging role: t<92 stages x-f4 #t; 92<=t<184 stages y-f4 #(t-92)
    const bool isStage = (t < 184);
    const bool isX     = (t < 92);
    const int  fi      = isX ? t : (t - 92);   // f4 index in row, 0..91
    const float* src   = (isX ? X : Y) + (size_t)b * (H_ * W_) + 4 * fi;

    // compute role: 2 output cols per thread
    const int  c     = 2 * t;
    const bool colOK = (c < OW);               // t <= 180

    const float dr  = ws[b];
    float C1 = 0.01f * dr; C1 *= C1;
    float C2 = 0.03f * dr; C2 *= C2;
    const f2 c1v = f2{C1 * 2401.0f, C1 * 2401.0f};   // scaled-domain constants
    const f2 c2v = f2{C2 * 2401.0f, C2 * 2401.0f};
    const f2 two    = f2{2.0f, 2.0f};
    const f2 k49    = f2{49.0f, 49.0f};
    const f2 covn2v = f2{2.0f * (49.0f / 48.0f), 2.0f * (49.0f / 48.0f)};
    const f2 covnv  = f2{49.0f / 48.0f, 49.0f / 48.0f};

    // ---- staging prime: load rows r0..r0+7 (always in-bounds: r0 <= 620),
    //      write rows r0..r0+6 to slots 0..6, keep row r0+7 in bufA ----
    f4 bufA;
    {
        f4 pr[8];
        if (isStage) {
            #pragma unroll
            for (int k = 0; k < 8; ++k)
                pr[k] = *(const f4*)(src + (size_t)(r0 + k) * W_);
            #pragma unroll
            for (int k = 0; k < 7; ++k)
                *(f4*)((isX ? lx[k] : ly[k]) + 4 * fi) = pr[k];
            bufA = pr[7];
        }
    }
    __syncthreads();                           // prime rows visible

    // ---- compute prime: ring from LDS rows 0..5 ----
    f2 ring[5][7];
    f2 tot[5] = {f2{0,0}, f2{0,0}, f2{0,0}, f2{0,0}, f2{0,0}};
    f2 h[5];
    f2 acc2 = f2{0.0f, 0.0f};
    if (colOK) {
        #pragma unroll
        for (int p = 0; p < 6; ++p) {
            hsum2l(&lx[p][c], &ly[p][c], h);
            #pragma unroll
            for (int q = 0; q < 5; ++q) { ring[q][p] = h[q]; tot[q] += h[q]; }
        }
    }

    // ---- main loop: one barrier per row; ring slots stay compile-time (p) ----
    for (int ii = 0; ii < outRows; ii += 7) {
        #pragma unroll
        for (int p = 0; p < 7; ++p) {
            const int i = ii + p;
            if (i >= outRows) break;           // block-uniform
            // Barrier: (a) row i+6 (written at iter i-1) becomes visible;
            // (b) slot (i+7)&7's old content (row i-1) was last READ 6 iters ago.
            __syncthreads();
            if (isStage && i <= outRows - 2) { // write row r0+i+7, prefetch r0+i+8
                *(f4*)((isX ? lx[(i + 7) & 7] : ly[(i + 7) & 7]) + 4 * fi) = bufA;
                int rn = r0 + i + 8; if (rn > H_ - 1) rn = H_ - 1;  // clamp; value unused if OOB
                bufA = *(const f4*)(src + (size_t)rn * W_);
            }
            if (colOK) {
                const int s = (i + 6) & 7;     // LDS slot of new row r0+i+6
                hsum2l(&lx[s][c], &ly[s][c], h);
                #pragma unroll
                for (int q = 0; q < 5; ++q) tot[q] += h[q];

                const f2 tx = tot[0], ty = tot[1], txx = tot[2], tyy = tot[3], txy = tot[4];
                const f2 pxy = tx * ty;
                const f2 A1  = ffma2(pxy, two, c1v);
                const f2 s2  = ffma2(tx, tx, ty * ty);
                const f2 B1  = s2 + c1v;
                const f2 mxy = ffma2(k49, txy, -pxy);
                const f2 A2  = ffma2(covn2v, mxy, c2v);
                const f2 vs  = ffma2(k49, txx + tyy, -s2);
                const f2 B2  = ffma2(covnv, vs, c2v);
                const f2 num = A1 * A2;
                const f2 den = B1 * B2;
                f2 r;
                r.x = __builtin_amdgcn_rcpf(den.x);
                r.y = __builtin_amdgcn_rcpf(den.y);
                acc2 = ffma2(num, r, acc2);

                const int sn = (p + 6) % 7;    // retire slot p, insert at sn (compile-time)
                #pragma unroll
                for (int q = 0; q < 5; ++q) { tot[q] -= ring[q][p]; ring[q][sn] = h[q]; }
            }
        }
    }

    // ---- reduction: wave -> LDS(4) -> one scattered atomic; hierarchical completion ----
    float acc = acc2.x + acc2.y;
    #pragma unroll
    for (int off = 32; off; off >>= 1)
        acc += __shfl_down(acc, off, 64);
    __shared__ float smr[4];
    __syncthreads();                           // loop's last readers done before reuse is moot (separate array) but cheap
    if (lane == 0) smr[w] = acc;
    __syncthreads();
    if (t == 0) {
        const float s = (smr[0] + smr[1]) + (smr[2] + smr[3]);
        const int blk = blockIdx.y * NCHUNK + blockIdx.x;
        const unsigned g = (unsigned)(blk & (GROUPS - 1));
        float* slots = ws + SLOT0;
        // s_waitcnt = wave-local drain ordering slot-add -> count (no buffer_inv;
        // __threadfence's L1 wipe killed R5). Hierarchical counters: R8's single
        // address serialized 2048 RMWs (~62 us).
        atomicAdd(&slots[g * STRIDE], s);      // 64 independent lines
        __builtin_amdgcn_s_waitcnt(0);
        unsigned* cnt1 = (unsigned*)(ws + CNT0);
        const unsigned d1 = atomicAdd(&cnt1[g * STRIDE], 1u);
        if (d1 == PER_GROUP - 1) {             // group complete (16 blocks)
            __builtin_amdgcn_s_waitcnt(0);
            const unsigned d2 = atomicAdd((unsigned*)(ws + ROOTC), 1u);
            if (d2 == GROUPS - 1) {            // all complete: finalize
                float totsum = 0.0f;
                #pragma unroll
                for (int i = 0; i < GROUPS; ++i)
                    totsum += atomicAdd(&slots[i * STRIDE], 0.0f);   // L2-coherent reads
                out[0] = 1.0f - totsum * (1.0f / (32.0f * 634.0f * 362.0f));
            }
        }
    }
}

extern "C" void kernel_launch(void* const* d_in, const int* in_sizes, int n_in,
                              void* d_out, int out_size, void* d_ws, size_t ws_size,
                              hipStream_t stream) {
    const float* X = (const float*)d_in[0];   // 'output'
    const float* Y = (const float*)d_in[1];   // 'target'
    float* ws = (float*)d_ws;

    k_max<<<dim3(2048), dim3(256), 0, stream>>>(Y, ws);
    k_ssim<<<dim3(NCHUNK, B_), dim3(256), 0, stream>>>(X, Y, ws, (float*)d_out);
}

// Round 12
// 139.959 us; speedup vs baseline: 1.0146x; 1.0132x over previous
//
#include <hip/hip_runtime.h>

#define B_    32
#define H_    640
#define W_    368
#define OH    634          // H - 6
#define OW    362          // W - 6
#define CHUNK 20           // output rows per block
#define NCHUNK 32          // 31 full chunks + last (14 rows); 31*20+14 = 634
#define NBLK  (NCHUNK * B_)          // 1024
#define GROUPS 64
#define PER_GROUP (NBLK / GROUPS)    // 16

// d_ws layout (floats):
//   [0..31]      per-batch max of target (int-bits atomicMax; 0xAA poison is negative,
//                any positive-float bits win, so no pre-zeroing needed)
//   [64..1087]   64 partial-sum slots, stride 16 floats (64 B); zeroed by k_max blk 0
//   [1088..2111] 64 group counters (uint), stride 16; zeroed by k_max blk 0
//   [2112]       root counter (uint, own line); zeroed by k_max blk 0
#define SLOT0 64
#define CNT0  1088
#define ROOTC 2112
#define STRIDE 16

typedef float f2 __attribute__((ext_vector_type(2)));
typedef float f4 __attribute__((ext_vector_type(4)));
__device__ __forceinline__ f2 ffma2(f2 a, f2 b, f2 c) { return __builtin_elementwise_fma(a, b, c); }

__global__ __launch_bounds__(256) void k_max(const float* __restrict__ tgt,
                                             float* __restrict__ ws) {
    if (blockIdx.x == 0) {                     // zero slots + counters (stream order vs k_ssim)
        for (int i = threadIdx.x; i < 2 * GROUPS * STRIDE + STRIDE; i += 256)
            ws[SLOT0 + i] = 0.0f;
    }
    const int b   = blockIdx.x >> 6;           // 64 segments per batch
    const int seg = blockIdx.x & 63;
    const int perseg = (H_ * W_) / 64;         // 3680 floats
    const float4* p = (const float4*)(tgt + (size_t)b * (H_ * W_) + (size_t)seg * perseg);
    const int n4 = perseg / 4;                 // 920
    float m = 0.0f;
    for (int i = threadIdx.x; i < n4; i += 256) {
        float4 v = p[i];
        m = fmaxf(m, fmaxf(fmaxf(v.x, v.y), fmaxf(v.z, v.w)));
    }
    #pragma unroll
    for (int off = 32; off; off >>= 1)
        m = fmaxf(m, __shfl_down(m, off, 64));
    __shared__ float sm[4];
    const int lane = threadIdx.x & 63, wv = threadIdx.x >> 6;
    if (lane == 0) sm[wv] = m;
    __syncthreads();
    if (threadIdx.x == 0) {
        m = fmaxf(fmaxf(sm[0], sm[1]), fmaxf(sm[2], sm[3]));
        atomicMax((int*)ws + b, __float_as_int(m));   // inputs >= 0
    }
}

// Horizontal 7-sums for TWO adjacent windows (cols c..c+6, c+1..c+7) read from
// LDS (8-byte aligned: addr (row*368 + 2t)*4). h = {x,y,xx,yy,xy} as {win0,win1}.
__device__ __forceinline__ void hsum2l(const float* __restrict__ xr,
                                       const float* __restrict__ yr,
                                       f2 h[5]) {
    float xs[8], ys[8];
    #pragma unroll
    for (int k = 0; k < 4; ++k) {
        const f2 a = ((const f2*)xr)[k];
        const f2 d = ((const f2*)yr)[k];
        xs[2*k] = a.x; xs[2*k+1] = a.y;
        ys[2*k] = d.x; ys[2*k+1] = d.y;
    }
    float hx = 0, hy = 0, hxx = 0, hyy = 0, hxy = 0;
    #pragma unroll
    for (int k = 0; k < 7; ++k) {
        const float xv = xs[k], yv = ys[k];
        hx += xv; hy += yv;
        hxx = fmaf(xv, xv, hxx);
        hyy = fmaf(yv, yv, hyy);
        hxy = fmaf(xv, yv, hxy);
    }
    h[0] = f2{hx,  hx - xs[0] + xs[7]};
    h[1] = f2{hy,  hy - ys[0] + ys[7]};
    h[2] = f2{hxx, fmaf(xs[7], xs[7], fmaf(-xs[0], xs[0], hxx))};
    h[3] = f2{hyy, fmaf(ys[7], ys[7], fmaf(-ys[0], ys[0], hyy))};
    h[4] = f2{hxy, fmaf(xs[7], ys[7], fmaf(-xs[0], ys[0], hxy))};
}

// Phase-batched LDS staging: 4 rows per __syncthreads (R11 staged 1 row/barrier;
// the barrier's implicit vmcnt(0) drained a ~900-cyc prefetch against ~200 cyc of
// compute EVERY row). Here each phase writes 4 prefetched rows, issues the next 4
// loads, then computes 4 rows (~840 cyc cover) before the next barrier.
// 16-row LDS ring (47 KB, 3 blocks/CU). Register ring = 8 slots, index
// (4*ph+p4)&7 is a literal (phases unrolled in pairs) — no R6-style scratch.
__global__ __launch_bounds__(256) void k_ssim(const float* __restrict__ X,
                                              const float* __restrict__ Y,
                                              float* __restrict__ ws,
                                              float* __restrict__ out) {
    const int t    = threadIdx.x;              // 0..255
    const int w    = t >> 6;
    const int lane = t & 63;
    const int b    = blockIdx.y;
    const int r0   = blockIdx.x * CHUNK;
    const int outRows = min(CHUNK, OH - r0);   // 20, or 14 for last chunk

    __shared__ __align__(16) float lx[16][W_];
    __shared__ __align__(16) float ly[16][W_];

    // staging role: t<92 stages x f4-column #t; 92<=t<184 stages y f4-column #(t-92)
    const bool isStage = (t < 184);
    const bool isX     = (t < 92);
    const int  fi      = isX ? t : (t - 92);   // f4 index in row, 0..91
    const float* src   = (isX ? X : Y) + (size_t)b * (H_ * W_) + 4 * fi;
    float* ldst        = isX ? &lx[0][0] : &ly[0][0];

    // compute role: 2 output cols per thread
    const int  c     = 2 * t;
    const bool colOK = (c < OW);               // t <= 180

    const float dr  = ws[b];
    float C1 = 0.01f * dr; C1 *= C1;
    float C2 = 0.03f * dr; C2 *= C2;
    const f2 c1v = f2{C1 * 2401.0f, C1 * 2401.0f};   // scaled-domain constants
    const f2 c2v = f2{C2 * 2401.0f, C2 * 2401.0f};
    const f2 two    = f2{2.0f, 2.0f};
    const f2 k49    = f2{49.0f, 49.0f};
    const f2 covn2v = f2{2.0f * (49.0f / 48.0f), 2.0f * (49.0f / 48.0f)};
    const f2 covnv  = f2{49.0f / 48.0f, 49.0f / 48.0f};

    // ---- prime: stage rows r0..r0+11 (slots 0..11), prefetch rows r0+12..15 ----
    f4 nxt[4];
    if (isStage) {
        #pragma unroll
        for (int k = 0; k < 12; ++k) {         // r0+11 <= 631 < 640: in-bounds
            const f4 v = *(const f4*)(src + (size_t)(r0 + k) * W_);
            *(f4*)(ldst + k * W_ + 4 * fi) = v;
        }
        #pragma unroll
        for (int k = 0; k < 4; ++k)            // r0+15 <= 635: in-bounds
            nxt[k] = *(const f4*)(src + (size_t)(r0 + 12 + k) * W_);
    }
    __syncthreads();                           // prime rows visible

    // ---- compute prime: register ring from LDS rows 0..5 (slot = row & 7) ----
    f2 ring[5][8];
    f2 tot[5] = {f2{0,0}, f2{0,0}, f2{0,0}, f2{0,0}, f2{0,0}};
    f2 h[5];
    f2 acc2 = f2{0.0f, 0.0f};
    if (colOK) {
        #pragma unroll
        for (int p = 0; p < 6; ++p) {
            hsum2l(&lx[p][c], &ly[p][c], h);
            #pragma unroll
            for (int q = 0; q < 5; ++q) { ring[q][p] = h[q]; tot[q] += h[q]; }
        }
    }

    // ---- main: phases of 4 rows, unrolled in pairs so ring indices are literals ----
    for (int ii = 0; ii < outRows; ii += 8) {
        #pragma unroll
        for (int ph = 0; ph < 2; ++ph) {
            const int base = ii + 4 * ph;
            if (base >= outRows) break;        // block-uniform
            __syncthreads();                   // phase boundary (drains prior phase's loads)
            if (isStage) {
                if (base + 4 < outRows) {      // write rows r0+base+12..15 (needed by phase base+4)
                    #pragma unroll
                    for (int k = 0; k < 4; ++k)
                        *(f4*)(ldst + ((base + 12 + k) & 15) * W_ + 4 * fi) = nxt[k];
                }
                if (base + 8 < outRows) {      // issue rows r0+base+16..19 (consumed at phase base+4)
                    #pragma unroll
                    for (int k = 0; k < 4; ++k) {
                        int rn = r0 + base + 16 + k;
                        rn = min(rn, H_ - 1);  // clamp (last block only; extra read harmless)
                        nxt[k] = *(const f4*)(src + (size_t)rn * W_);
                    }
                }
            }
            if (colOK) {
                #pragma unroll
                for (int p4 = 0; p4 < 4; ++p4) {
                    const int i = base + p4;
                    if (i >= outRows) break;   // block-uniform
                    const int sR = (4 * ph + p4) & 7;       // literal: ring slot of row i
                    const int sW = (4 * ph + p4 + 6) & 7;   // literal: slot for row i+6
                    const int sl = (i + 6) & 15;            // LDS slot (runtime OK)
                    hsum2l(&lx[sl][c], &ly[sl][c], h);
                    #pragma unroll
                    for (int q = 0; q < 5; ++q) tot[q] += h[q];

                    const f2 tx = tot[0], ty = tot[1], txx = tot[2], tyy = tot[3], txy = tot[4];
                    const f2 pxy = tx * ty;
                    const f2 A1  = ffma2(pxy, two, c1v);
                    const f2 s2  = ffma2(tx, tx, ty * ty);
                    const f2 B1  = s2 + c1v;
                    const f2 mxy = ffma2(k49, txy, -pxy);
                    const f2 A2  = ffma2(covn2v, mxy, c2v);
                    const f2 vs  = ffma2(k49, txx + tyy, -s2);
                    const f2 B2  = ffma2(covnv, vs, c2v);
                    const f2 num = A1 * A2;
                    const f2 den = B1 * B2;
                    f2 r;
                    r.x = __builtin_amdgcn_rcpf(den.x);
                    r.y = __builtin_amdgcn_rcpf(den.y);
                    acc2 = ffma2(num, r, acc2);

                    #pragma unroll
                    for (int q = 0; q < 5; ++q) { tot[q] -= ring[q][sR]; ring[q][sW] = h[q]; }
                }
            }
        }
    }

    // ---- reduction: wave -> LDS(4) -> scattered atomic; hierarchical completion ----
    float acc = acc2.x + acc2.y;
    #pragma unroll
    for (int off = 32; off; off >>= 1)
        acc += __shfl_down(acc, off, 64);
    __shared__ float smr[4];
    if (lane == 0) smr[w] = acc;
    __syncthreads();
    if (t == 0) {
        const float s = (smr[0] + smr[1]) + (smr[2] + smr[3]);
        const int blk = blockIdx.y * NCHUNK + blockIdx.x;
        const unsigned g = (unsigned)(blk & (GROUPS - 1));
        float* slots = ws + SLOT0;
        // s_waitcnt = wave-local drain ordering slot-add -> count (no buffer_inv;
        // __threadfence's L1 wipe killed R5). Hierarchical counters: a single
        // address serialized 2048 RMWs (~62 us) in R8.
        atomicAdd(&slots[g * STRIDE], s);      // 64 independent lines
        __builtin_amdgcn_s_waitcnt(0);
        unsigned* cnt1 = (unsigned*)(ws + CNT0);
        const unsigned d1 = atomicAdd(&cnt1[g * STRIDE], 1u);
        if (d1 == PER_GROUP - 1) {             // group complete (16 blocks)
            __builtin_amdgcn_s_waitcnt(0);
            const unsigned d2 = atomicAdd((unsigned*)(ws + ROOTC), 1u);
            if (d2 == GROUPS - 1) {            // all complete: finalize
                float totsum = 0.0f;
                #pragma unroll
                for (int i = 0; i < GROUPS; ++i)
                    totsum += atomicAdd(&slots[i * STRIDE], 0.0f);   // L2-coherent reads
                out[0] = 1.0f - totsum * (1.0f / (32.0f * 634.0f * 362.0f));
            }
        }
    }
}

extern "C" void kernel_launch(void* const* d_in, const int* in_sizes, int n_in,
                              void* d_out, int out_size, void* d_ws, size_t ws_size,
                              hipStream_t stream) {
    const float* X = (const float*)d_in[0];   // 'output'
    const float* Y = (const float*)d_in[1];   // 'target'
    float* ws = (float*)d_ws;

    k_max<<<dim3(2048), dim3(256), 0, stream>>>(Y, ws);
    k_ssim<<<dim3(NCHUNK, B_), dim3(256), 0, stream>>>(X, Y, ws, (float*)d_out);
}